// Round 4
// baseline (987.409 us; speedup 1.0000x reference)
//
#include <hip/hip_runtime.h>
#include <hip/hip_bf16.h>

#define DEVI __device__ __forceinline__

constexpr int B_   = 8;
constexpr int L_   = 4097;
constexpr int MTOT = B_ * L_;          // 32776 tokens
constexpr int DH   = 384;              // d_half
constexpr int NS   = 16;               // d_state
constexpr int CH   = 128;              // scan chunk length
constexpr int NCH  = (L_ + CH - 1) / CH;  // 33 chunks (last has 1 token)

DEVI float bl(unsigned v) { return __uint_as_float(v << 16); }          // low bf16
DEVI float bh(unsigned v) { return __uint_as_float(v & 0xffff0000u); }  // high bf16
DEVI float bf(const __hip_bfloat16 x) { return __bfloat162float(x); }

// ---------------------------------------------------------------------------
// dtype detector: hidden_states ~ N(0,1). If bf16, every u16 is a bf16 with
// exponent field ~126. If fp32, even-index u16 are mantissa bits (uniform
// exponent field). flag=1 -> bf16 inputs, flag=0 -> fp32 inputs.
// ---------------------------------------------------------------------------
__global__ void flag_k(const void* hs, int* flagp) {
  if (threadIdx.x == 0 && blockIdx.x == 0) {
    const unsigned short* u = (const unsigned short*)hs;
    int ok = 1;
    for (int i = 0; i < 8; ++i) {
      const unsigned short v = u[2 * i];
      const int e = (v >> 7) & 0xFF;
      if (!(v == 0 || (e >= 100 && e <= 140))) ok = 0;
    }
    flagp[0] = ok;
  }
}

// ---------------------------------------------------------------------------
// perm normalizer: int64 vs int32 detection. Values are 0..4095, so int64
// storage has all odd int32 words == 0 in the first 4096 ints (16 KB, always
// in-bounds). int32 storage is a permutation slice -> OR != 0.
// ---------------------------------------------------------------------------
__global__ void perm_k(const int* p0, const int* p1, int* d0, int* d1) {
  __shared__ int s_or;
  const int* src = blockIdx.x ? p1 : p0;
  int*       dst = blockIdx.x ? d1 : d0;
  if (threadIdx.x == 0) s_or = 0;
  __syncthreads();
  int loc = 0;
  for (int i = threadIdx.x; i < 2048; i += 1024) loc |= src[2 * i + 1];
  atomicOr(&s_or, loc);
  __syncthreads();
  const bool is64 = (s_or == 0);
  for (int j = threadIdx.x; j < 4096; j += 1024)
    dst[j] = is64 ? (int)((const long long*)src)[j] : src[j];
}

// ---------------------------------------------------------------------------
// normalize a float tensor (bf16 or fp32 storage, per flag) to bf16
// ---------------------------------------------------------------------------
__global__ void norm_k(const void* src, __hip_bfloat16* dst, int n,
                       const int* flagp) {
  const int i = blockIdx.x * 256 + threadIdx.x;
  if (i >= n) return;
  if (flagp[0]) dst[i] = ((const __hip_bfloat16*)src)[i];
  else          dst[i] = __float2bfloat16(((const float*)src)[i]);
}

// ---------------------------------------------------------------------------
// Wcomb bf16 (416 x 384): rows 0..383 = dt_proj_w @ x_proj_w[0:24] (fused dt
// matrix), rows 384..415 = x_proj_w[24:56] (B then C).
// ---------------------------------------------------------------------------
__global__ void prep_k(const __hip_bfloat16* __restrict__ dtw,
                       const __hip_bfloat16* __restrict__ xw,
                       __hip_bfloat16* __restrict__ wcomb) {
  const int idx = blockIdx.x * 256 + threadIdx.x;
  if (idx >= 416 * 384) return;
  const int n = idx / 384, k = idx - n * 384;
  float v = 0.f;
  if (n < 384) {
#pragma unroll
    for (int r = 0; r < 24; ++r) v += bf(dtw[n * 24 + r]) * bf(xw[r * 384 + k]);
  } else {
    v = bf(xw[(24 + n - 384) * 384 + k]);
  }
  wcomb[idx] = __float2bfloat16(v);
}

// ---------------------------------------------------------------------------
// fp32 VALU GEMM: C[m,n] = sum_k A[src(m),k] * W[n,k], K=384.
// Tile 128(M) x 64(N), BK=16, 256 threads, 8x4 outputs/thread, fp32 LDS.
// AD=0: A is bf16. AD=1: A is hs, dtype selected by runtime flag.
// GATHER: A row gathered via normalized perm. EPI: 0=in_proj split (bf16 x2),
// 1=dt softplus (bf16) + B/C (fp32), 2=final out (bf16 or fp32 per flag).
// ---------------------------------------------------------------------------
template<int AD, int GATHER, int EPI>
__global__ __launch_bounds__(256)
void vgemm(const void* __restrict__ Av, const __hip_bfloat16* __restrict__ Wb,
           void* __restrict__ e0, void* __restrict__ e1,
           const __hip_bfloat16* __restrict__ bias,
           const int* __restrict__ gidx, const int* __restrict__ flagp,
           int M, int N)
{
  __shared__ float sA[16][132];   // [k][m], +4 pad
  __shared__ float sB[16][68];    // [k][n], +4 pad
  const int tid = threadIdx.x;
  const int mt = blockIdx.x, nt = blockIdx.y;
  const int fbf = flagp[0];       // 1 = bf16 external storage

  int am = mt * 128 + (tid >> 1);
  if (am >= M) am = M - 1;
  int asrc;
  if (GATHER) { const int b = am / L_, t = am - b * L_;
                asrc = b * L_ + (t == 0 ? 0 : 1 + gidx[t - 1]); }
  else        { asrc = am; }
  const int akg = (tid & 1) * 8;
  int wn = nt * 64 + (tid >> 2);
  if (wn >= N) wn = N - 1;
  const int wkg = (tid & 3) * 4;

  const __hip_bfloat16* Ab = (const __hip_bfloat16*)Av;
  const float*          Af = (const float*)Av;

  float acc[8][4] = {};
  const int ty = tid >> 4, tx = tid & 15;   // m0 = ty*8, n0 = tx*4

  for (int kt = 0; kt < 384; kt += 16) {
    float a8[8], w4[4];
    if (AD == 1 && !fbf) {                  // fp32 A storage
      const float4 f0 = *(const float4*)(Af + (size_t)asrc * 384 + kt + akg);
      const float4 f1 = *(const float4*)(Af + (size_t)asrc * 384 + kt + akg + 4);
      a8[0] = f0.x; a8[1] = f0.y; a8[2] = f0.z; a8[3] = f0.w;
      a8[4] = f1.x; a8[5] = f1.y; a8[6] = f1.z; a8[7] = f1.w;
    } else {                                // bf16 A storage
      const uint4 u = *(const uint4*)(Ab + (size_t)asrc * 384 + kt + akg);
      a8[0] = bl(u.x); a8[1] = bh(u.x); a8[2] = bl(u.y); a8[3] = bh(u.y);
      a8[4] = bl(u.z); a8[5] = bh(u.z); a8[6] = bl(u.w); a8[7] = bh(u.w);
    }
    {
      const uint2 u = *(const uint2*)(Wb + (size_t)wn * 384 + kt + wkg);
      w4[0] = bl(u.x); w4[1] = bh(u.x); w4[2] = bl(u.y); w4[3] = bh(u.y);
    }
    __syncthreads();                        // WAR: prior reads done
#pragma unroll
    for (int j = 0; j < 8; ++j) sA[akg + j][tid >> 1] = a8[j];
#pragma unroll
    for (int j = 0; j < 4; ++j) sB[wkg + j][tid >> 2] = w4[j];
    __syncthreads();                        // staged data visible
#pragma unroll
    for (int kk = 0; kk < 16; ++kk) {
      const float4 a0 = *(const float4*)&sA[kk][ty * 8];
      const float4 a1 = *(const float4*)&sA[kk][ty * 8 + 4];
      const float4 b0 = *(const float4*)&sB[kk][tx * 4];
      const float av[8] = {a0.x, a0.y, a0.z, a0.w, a1.x, a1.y, a1.z, a1.w};
      const float bv[4] = {b0.x, b0.y, b0.z, b0.w};
#pragma unroll
      for (int i = 0; i < 8; ++i)
#pragma unroll
        for (int j = 0; j < 4; ++j) acc[i][j] += av[i] * bv[j];
    }
  }

#pragma unroll
  for (int i = 0; i < 8; ++i) {
    const int r = mt * 128 + ty * 8 + i;
    if (r >= M) continue;
#pragma unroll
    for (int j = 0; j < 4; ++j) {
      const int col = nt * 64 + tx * 4 + j;
      if (col >= N) continue;
      const float v = acc[i][j];
      if (EPI == 0) {          // in_proj: x half -> e0 (bf16), z half -> e1 (bf16)
        if (col < 384) ((__hip_bfloat16*)e0)[(size_t)r * 384 + col] = __float2bfloat16(v);
        else           ((__hip_bfloat16*)e1)[(size_t)r * 384 + (col - 384)] = __float2bfloat16(v);
      } else if (EPI == 1) {   // dt: bias+softplus -> e0 (bf16); B/C -> e1 (fp32)
        if (col < 384) {
          const float x = v + bf(bias[col]);
          const float sp = (x > 20.f) ? x : log1pf(__expf(x));
          ((__hip_bfloat16*)e0)[(size_t)r * 384 + col] = __float2bfloat16(sp);
        } else {
          ((float*)e1)[(size_t)r * 32 + (col - 384)] = v;
        }
      } else {                 // final out: dtype per flag
        if (fbf) ((__hip_bfloat16*)e0)[(size_t)r * 384 + col] = __float2bfloat16(v);
        else     ((float*)e0)[(size_t)r * 384 + col] = v;
      }
    }
  }
}

// ---------------------------------------------------------------------------
// depthwise conv k=4 (taps t-1..t+2) + silu on the x half (bf16 in/out)
// ---------------------------------------------------------------------------
__global__ void convx_k(const __hip_bfloat16* __restrict__ xh,
                        const __hip_bfloat16* __restrict__ cxw,
                        __hip_bfloat16* __restrict__ xc) {
  const int idx = blockIdx.x * 256 + threadIdx.x;
  if (idx >= MTOT * 384) return;
  const int c = idx % 384;
  const int rg = idx / 384;
  const int t = rg % L_;
  float acc = 0.f;
#pragma unroll
  for (int k = 0; k < 4; ++k) {
    const int tt = t + k - 1;
    if (tt >= 0 && tt < L_)
      acc += bf(cxw[c * 4 + k]) * bf(xh[(size_t)(rg + k - 1) * 384 + c]);
  }
  const float s = acc / (1.f + __expf(-acc));
  xc[idx] = __float2bfloat16(s);
}

// ---------------------------------------------------------------------------
// scan phase 1: per (b, chunk, d) local scan with h0=0; emits chunk decay
// P = exp2(sum(dt)*a2) and local h_end. Layout: [(c*8+b)*16+n]*384+d.
// ---------------------------------------------------------------------------
__global__ __launch_bounds__(128)
void scan1_k(const __hip_bfloat16* __restrict__ dt, const float* __restrict__ bc,
             const __hip_bfloat16* __restrict__ xc,
             const __hip_bfloat16* __restrict__ alog,
             float* __restrict__ pbuf, float* __restrict__ hend)
{
  __shared__ float lBC[CH * 32];
  const int blk = blockIdx.x;
  const int dt3 = blk % 3;
  const int c   = (blk / 3) % NCH;
  const int b   = blk / (3 * NCH);
  const int d   = dt3 * 128 + threadIdx.x;
  const int t0  = c * CH;
  const int r0  = b * L_ + t0;
  const int tmax = (L_ - t0 < CH) ? (L_ - t0) : CH;
  for (int i = threadIdx.x; i < tmax * 32; i += 128) lBC[i] = bc[(size_t)r0 * 32 + i];
  __syncthreads();

  float a2[16];
#pragma unroll
  for (int n = 0; n < 16; ++n)
    a2[n] = -1.4426950408889634f * __expf(bf(alog[d * 16 + n]));  // A * log2(e)
  float h[16];
#pragma unroll
  for (int n = 0; n < 16; ++n) h[n] = 0.f;
  float sdt = 0.f;

  for (int tt = 0; tt < tmax; ++tt) {
    const size_t r = (size_t)(r0 + tt);
    const float dtv = bf(dt[r * 384 + d]);
    const float xv  = bf(xc[r * 384 + d]);
    sdt += dtv;
    const float dtx = dtv * xv;
#pragma unroll
    for (int n = 0; n < 16; ++n)
      h[n] = h[n] * exp2f(dtv * a2[n]) + dtx * lBC[tt * 32 + n];
  }
  const size_t base = ((size_t)(c * 8 + b) * 16) * 384 + d;
#pragma unroll
  for (int n = 0; n < 16; ++n) {
    pbuf[base + n * 384] = exp2f(sdt * a2[n]);
    hend[base + n * 384] = h[n];
  }
}

// ---------------------------------------------------------------------------
// scan phase 2: cross-chunk scan per (b,d,n); rewrites pbuf with h_start
// ---------------------------------------------------------------------------
__global__ void scan2_k(float* __restrict__ pbuf, const float* __restrict__ hend) {
  const int tid = blockIdx.x * 256 + threadIdx.x;   // 49152 total
  const int d = tid % 384;
  const int n = (tid / 384) & 15;
  const int b = tid / 6144;
  float H = 0.f;
  for (int c = 0; c < NCH; ++c) {
    const size_t idx = ((size_t)(c * 8 + b) * 16 + n) * 384 + d;
    const float p = pbuf[idx];
    const float he = hend[idx];
    pbuf[idx] = H;
    H = p * H + he;
  }
}

// ---------------------------------------------------------------------------
// scan phase 3: recompute with h_start; fused z-conv + silu gate; writes
// yg = (y + D*x) * silu(conv(z)) IN PLACE over dt (same-thread read-then-write).
// ---------------------------------------------------------------------------
__global__ __launch_bounds__(128)
void scan3_k(__hip_bfloat16* dtyg, const float* __restrict__ bc,
             const __hip_bfloat16* __restrict__ xc,
             const __hip_bfloat16* __restrict__ zh,
             const __hip_bfloat16* __restrict__ czw,
             const __hip_bfloat16* __restrict__ alog,
             const __hip_bfloat16* __restrict__ dpar,
             const float* __restrict__ hstart)
{
  __shared__ float lBC[CH * 32];
  const int blk = blockIdx.x;
  const int dt3 = blk % 3;
  const int c   = (blk / 3) % NCH;
  const int b   = blk / (3 * NCH);
  const int d   = dt3 * 128 + threadIdx.x;
  const int t0  = c * CH;
  const int r0  = b * L_ + t0;
  const int tmax = (L_ - t0 < CH) ? (L_ - t0) : CH;
  for (int i = threadIdx.x; i < tmax * 32; i += 128) lBC[i] = bc[(size_t)r0 * 32 + i];
  __syncthreads();

  float a2[16];
#pragma unroll
  for (int n = 0; n < 16; ++n)
    a2[n] = -1.4426950408889634f * __expf(bf(alog[d * 16 + n]));
  float h[16];
  const size_t base = ((size_t)(c * 8 + b) * 16) * 384 + d;
#pragma unroll
  for (int n = 0; n < 16; ++n) h[n] = hstart[base + n * 384];
  const float Dd = bf(dpar[d]);
  float cw[4];
#pragma unroll
  for (int k = 0; k < 4; ++k) cw[k] = bf(czw[d * 4 + k]);

  float zm1 = (t0 - 1 >= 0) ? bf(zh[(size_t)(r0 - 1) * 384 + d]) : 0.f;
  float z0  = bf(zh[(size_t)r0 * 384 + d]);
  float zp1 = (t0 + 1 < L_) ? bf(zh[(size_t)(r0 + 1) * 384 + d]) : 0.f;

  for (int tt = 0; tt < tmax; ++tt) {
    const int t = t0 + tt;
    const size_t r = (size_t)(r0 + tt);
    const float zp2 = (t + 2 < L_) ? bf(zh[(r + 2) * 384 + d]) : 0.f;
    const float dtv = bf(dtyg[r * 384 + d]);
    const float xv  = bf(xc[r * 384 + d]);
    const float dtx = dtv * xv;
    float y = 0.f;
#pragma unroll
    for (int n = 0; n < 16; ++n) {
      h[n] = h[n] * exp2f(dtv * a2[n]) + dtx * lBC[tt * 32 + n];
      y += h[n] * lBC[tt * 32 + 16 + n];
    }
    y += Dd * xv;
    const float zc = cw[0] * zm1 + cw[1] * z0 + cw[2] * zp1 + cw[3] * zp2;
    const float zs = zc / (1.f + __expf(-zc));
    dtyg[r * 384 + d] = __float2bfloat16(y * zs);
    zm1 = z0; z0 = zp1; zp1 = zp2;
  }
}

// ---------------------------------------------------------------------------
extern "C" void kernel_launch(void* const* d_in, const int* in_sizes, int n_in,
                              void* d_out, int out_size, void* d_ws, size_t ws_size,
                              hipStream_t stream) {
  const void* hs   = d_in[0];   // (8,4097,384) float (bf16 or fp32 -> detected)
  const void* w_in = d_in[1];   // (768,384)
  const void* cxw  = d_in[2];   // (384,1,4)
  const void* czw  = d_in[3];   // (384,1,4)
  const void* xw   = d_in[4];   // (56,384)
  const void* dtw  = d_in[5];   // (384,24)
  const void* dtb  = d_in[6];   // (384,)
  const void* alog = d_in[7];   // (384,16)
  const void* dpar = d_in[8];   // (384,)
  const void* ow   = d_in[9];   // (384,384)
  const int* perm  = (const int*)d_in[10];   // (4096,) int32 or int64 -> detected
  const int* permr = (const int*)d_in[11];   // (4096,)

  char* ws = (char*)d_ws;
  size_t off = 0;
  auto alloc = [&](size_t nbytes) -> char* {
    char* p = ws + off;
    off += (nbytes + 255) & ~(size_t)255;
    return p;
  };
  int* flag              = (int*)alloc(256);
  int* nperm             = (int*)alloc(4096 * 4);
  int* npermr            = (int*)alloc(4096 * 4);
  __hip_bfloat16* w_inb  = (__hip_bfloat16*)alloc(294912 * 2);
  __hip_bfloat16* cxwb   = (__hip_bfloat16*)alloc(1536 * 2);
  __hip_bfloat16* czwb   = (__hip_bfloat16*)alloc(1536 * 2);
  __hip_bfloat16* xwb    = (__hip_bfloat16*)alloc(21504 * 2);
  __hip_bfloat16* dtwb   = (__hip_bfloat16*)alloc(9216 * 2);
  __hip_bfloat16* dtbb   = (__hip_bfloat16*)alloc(384 * 2);
  __hip_bfloat16* alogb  = (__hip_bfloat16*)alloc(6144 * 2);
  __hip_bfloat16* dparb  = (__hip_bfloat16*)alloc(384 * 2);
  __hip_bfloat16* owb    = (__hip_bfloat16*)alloc(147456 * 2);
  __hip_bfloat16* wcombb = (__hip_bfloat16*)alloc((size_t)416 * 384 * 2);
  __hip_bfloat16* zh     = (__hip_bfloat16*)alloc((size_t)MTOT * 384 * 2);  // 25.2 MB
  __hip_bfloat16* xc     = (__hip_bfloat16*)alloc((size_t)MTOT * 384 * 2);  // 25.2 MB
  __hip_bfloat16* dtyg   = (__hip_bfloat16*)alloc((size_t)MTOT * 384 * 2);  // 25.2 MB
  float*          bcf    = (float*)alloc((size_t)MTOT * 32 * 4);            // 4.2 MB
  // total ws ~ 81 MB. d_out doubles as scratch: xh (pre-conv x half, bf16,
  // 25.2 MB, dies at convx), then pbuf+hend (13 MB, die before final GEMM).
  __hip_bfloat16* xh   = (__hip_bfloat16*)d_out;
  float*          pbuf = (float*)d_out;
  float*          hend = (float*)((char*)d_out + (size_t)NCH * B_ * NS * DH * 4);

  // 0) dtype + perm-width detection, weight normalization to bf16
  flag_k<<<1, 64, 0, stream>>>(hs, flag);
  perm_k<<<2, 1024, 0, stream>>>(perm, permr, nperm, npermr);
  norm_k<<<(294912 + 255) / 256, 256, 0, stream>>>(w_in, w_inb, 294912, flag);
  norm_k<<<6, 256, 0, stream>>>(cxw, cxwb, 1536, flag);
  norm_k<<<6, 256, 0, stream>>>(czw, czwb, 1536, flag);
  norm_k<<<84, 256, 0, stream>>>(xw, xwb, 21504, flag);
  norm_k<<<36, 256, 0, stream>>>(dtw, dtwb, 9216, flag);
  norm_k<<<2, 256, 0, stream>>>(dtb, dtbb, 384, flag);
  norm_k<<<24, 256, 0, stream>>>(alog, alogb, 6144, flag);
  norm_k<<<2, 256, 0, stream>>>(dpar, dparb, 384, flag);
  norm_k<<<576, 256, 0, stream>>>(ow, owb, 147456, flag);
  // 1) fused dt/BC weight build
  prep_k<<<624, 256, 0, stream>>>(dtwb, xwb, wcombb);
  // 2) in_proj GEMM + permutation gather -> xh (in d_out), zh
  vgemm<1, 1, 0><<<dim3(257, 12), 256, 0, stream>>>(
      hs, w_inb, xh, zh, nullptr, nperm, flag, MTOT, 768);
  // 3) depthwise conv + silu on x half
  convx_k<<<(MTOT * 384 + 255) / 256, 256, 0, stream>>>(xh, cxwb, xc);
  // 4) fused dt (bias+softplus, bf16) and B/C (fp32) GEMM
  vgemm<0, 0, 1><<<dim3(257, 7), 256, 0, stream>>>(
      xc, wcombb, dtyg, bcf, dtbb, nullptr, flag, MTOT, 416);
  // 5) chunked selective scan (z-conv + gate fused into phase 3)
  scan1_k<<<B_ * NCH * 3, 128, 0, stream>>>(dtyg, bcf, xc, alogb, pbuf, hend);
  scan2_k<<<192, 256, 0, stream>>>(pbuf, hend);
  scan3_k<<<B_ * NCH * 3, 128, 0, stream>>>(dtyg, bcf, xc, zh, czwb, alogb,
                                            dparb, pbuf);
  // 6) out_proj GEMM with inverse-perm gather -> final output (dtype per flag)
  vgemm<0, 1, 2><<<dim3(257, 6), 256, 0, stream>>>(
      dtyg, owb, d_out, nullptr, nullptr, npermr, flag, MTOT, 384);
  (void)in_sizes; (void)n_in; (void)out_size; (void)ws_size;
}

// Round 7
// 659.253 us; speedup vs baseline: 1.4978x; 1.4978x over previous
//
#include <hip/hip_runtime.h>
#include <hip/hip_bf16.h>

#define DEVI __device__ __forceinline__

constexpr int B_   = 8;
constexpr int L_   = 4097;
constexpr int MTOT = B_ * L_;          // 32776 tokens
constexpr int DH   = 384;              // d_half
constexpr int NS   = 16;               // d_state
constexpr int CH   = 96;               // scan chunk length
constexpr int NCH  = (L_ + CH - 1) / CH;  // 43 chunks (last has 65 tokens)

typedef __bf16 bf16x8 __attribute__((ext_vector_type(8)));
typedef float  f32x4  __attribute__((ext_vector_type(4)));

DEVI float bl(unsigned v) { return __uint_as_float(v << 16); }          // low bf16
DEVI float bh(unsigned v) { return __uint_as_float(v & 0xffff0000u); }  // high bf16
DEVI float bf(const __hip_bfloat16 x) { return __bfloat162float(x); }
DEVI unsigned short f2bu(float x) {
  __hip_bfloat16 b = __float2bfloat16(x);
  return *(unsigned short*)&b;
}
DEVI float u16f(const uint4& u, int j) {   // element j (0..7) of 8 packed bf16
  const unsigned w = (&u.x)[j >> 1];
  return (j & 1) ? bh(w) : bl(w);
}

// ---------------------------------------------------------------------------
// dtype detector: hidden_states ~ N(0,1). bf16 -> every even u16 has exponent
// field ~126; fp32 -> even u16 are mantissa bits (uniform). flag=1 -> bf16.
// (round-4 evidence: harness preserves reference dtypes -> expect flag=0/fp32)
// ---------------------------------------------------------------------------
__global__ void flag_k(const void* hs, int* flagp) {
  if (threadIdx.x == 0 && blockIdx.x == 0) {
    const unsigned short* u = (const unsigned short*)hs;
    int ok = 1;
    for (int i = 0; i < 8; ++i) {
      const unsigned short v = u[2 * i];
      const int e = (v >> 7) & 0xFF;
      if (!(v == 0 || (e >= 100 && e <= 140))) ok = 0;
    }
    flagp[0] = ok;
  }
}

// ---------------------------------------------------------------------------
// perm normalizer: int64 storage has all odd int32 words zero (values<4096);
// int32 permutation cannot OR to zero over 2048 odd-index elements.
// (round-4-verified: harness delivers int64 -> this conversion is required)
// ---------------------------------------------------------------------------
__global__ void perm_k(const int* p0, const int* p1, int* d0, int* d1) {
  __shared__ int s_or;
  const int* src = blockIdx.x ? p1 : p0;
  int*       dst = blockIdx.x ? d1 : d0;
  if (threadIdx.x == 0) s_or = 0;
  __syncthreads();
  int loc = 0;
  for (int i = threadIdx.x; i < 2048; i += 1024) loc |= src[2 * i + 1];
  atomicOr(&s_or, loc);
  __syncthreads();
  const bool is64 = (s_or == 0);
  for (int j = threadIdx.x; j < 4096; j += 1024)
    dst[j] = is64 ? (int)((const long long*)src)[j] : src[j];
}

// ---------------------------------------------------------------------------
// fused normalization of all 9 weight tensors to bf16 (one launch)
// ---------------------------------------------------------------------------
struct NormSet { const void* src[9]; void* dst[9]; int n[9]; };
__global__ void norm_all(NormSet s, const int* flagp) {
  const int idx = blockIdx.x * 256 + threadIdx.x;
  const int f = flagp[0];
#pragma unroll
  for (int t = 0; t < 9; ++t) {
    if (idx < s.n[t]) {
      __hip_bfloat16* d = (__hip_bfloat16*)s.dst[t];
      if (f) d[idx] = ((const __hip_bfloat16*)s.src[t])[idx];
      else   d[idx] = __float2bfloat16(((const float*)s.src[t])[idx]);
    }
  }
}

// ---------------------------------------------------------------------------
// Wcomb bf16 (512 x 384): rows 0..383 = dt_proj_w @ x_proj_w[0:24] (fused dt
// matrix), rows 384..415 = x_proj_w[24:56] (B then C), rows 416..511 = 0.
// ---------------------------------------------------------------------------
__global__ void prep_k(const __hip_bfloat16* __restrict__ dtw,
                       const __hip_bfloat16* __restrict__ xw,
                       __hip_bfloat16* __restrict__ wcomb) {
  const int idx = blockIdx.x * 256 + threadIdx.x;
  if (idx >= 512 * 384) return;
  const int n = idx / 384, k = idx - n * 384;
  float v = 0.f;
  if (n < 384) {
#pragma unroll
    for (int r = 0; r < 24; ++r) v += bf(dtw[n * 24 + r]) * bf(xw[r * 384 + k]);
  } else if (n < 416) {
    v = bf(xw[(24 + n - 384) * 384 + k]);
  }
  wcomb[idx] = __float2bfloat16(v);
}

// ---------------------------------------------------------------------------
// MFMA GEMM: C[m,n] = sum_k A[src(m),k] * W[n,k], K=384, 128x128 tile,
// 4 waves x (4x4) 16x16x32 bf16 subtiles. Register->ds_write_b128 staging.
// Grid: (Ntiles, 257) with nt = blockIdx.x FASTEST for L2 A-reuse.
// ROUND-6 BUG FIX: fbf must ALWAYS come from the runtime flag. The AD ? ... : 1
// shortcut hard-wired the EPI==2 output to bf16 -- but the harness preserves
// the reference's float32 output dtype (proven by round-4 pass + int64 perm),
// so out_proj was writing bf16 pairs into an fp32 buffer -> full-scale error.
// ---------------------------------------------------------------------------
template<int AD, int GATHER, int EPI>
__global__ __launch_bounds__(256, 2)
void gemm_k(const void* __restrict__ Av, const __hip_bfloat16* __restrict__ W,
            void* __restrict__ e0, void* __restrict__ e1,
            const __hip_bfloat16* __restrict__ bias,
            const int* __restrict__ gidx, const int* __restrict__ flagp,
            int M, int N)
{
  __shared__ __align__(16) __hip_bfloat16 lA[128 * 32];
  __shared__ __align__(16) __hip_bfloat16 lB[128 * 32];
  const int tid  = threadIdx.x;
  const int lane = tid & 63;
  const int wv   = tid >> 6;
  const int wm   = wv >> 1, wn = wv & 1;
  const int nt   = blockIdx.x, mt = blockIdx.y;
  const int kcol = (lane & 3) * 8;        // element offset within BK=32 row
  const int fbf  = flagp[0];              // 1 = bf16 external storage

  // staging sources: each wave stages 2 x 16 rows of A and of W
  size_t aoff[2];
  const __hip_bfloat16* bg[2];
#pragma unroll
  for (int q = 0; q < 2; ++q) {
    const int seg = wv * 2 + q;
    int r = mt * 128 + seg * 16 + (lane >> 2);
    if (r >= M) r = M - 1;                // tail tile: duplicate a valid row
    int src;
    if (GATHER) { const int b = r / L_, t = r - b * L_;
                  src = b * L_ + (t == 0 ? 0 : 1 + gidx[t - 1]); }
    else        { src = r; }
    aoff[q] = (size_t)src * 384 + kcol;
    const int nr = nt * 128 + seg * 16 + (lane >> 2);
    bg[q] = W + (size_t)nr * 384 + kcol;
  }
  uint4* lAdst[2];
  uint4* lBdst[2];
#pragma unroll
  for (int q = 0; q < 2; ++q) {
    const int seg = wv * 2 + q;
    lAdst[q] = reinterpret_cast<uint4*>(&lA[seg * 512 + lane * 8]);
    lBdst[q] = reinterpret_cast<uint4*>(&lB[seg * 512 + lane * 8]);
  }

  f32x4 acc[4][4] = {};
  const int lrow = lane & 15, quad = lane >> 4;

  for (int kt = 0; kt < 12; ++kt) {       // K = 12 * 32
    uint4 ra[2], rb[2];
#pragma unroll
    for (int q = 0; q < 2; ++q) {         // issue global loads before barrier
      if (AD == 1 && !fbf) {              // fp32 A storage -> convert to bf16
        const float* f = (const float*)Av + aoff[q] + kt * 32;
        const float4 f0 = *(const float4*)f;
        const float4 f1 = *(const float4*)(f + 4);
        ra[q].x = f2bu(f0.x) | ((unsigned)f2bu(f0.y) << 16);
        ra[q].y = f2bu(f0.z) | ((unsigned)f2bu(f0.w) << 16);
        ra[q].z = f2bu(f1.x) | ((unsigned)f2bu(f1.y) << 16);
        ra[q].w = f2bu(f1.z) | ((unsigned)f2bu(f1.w) << 16);
      } else {
        ra[q] = *(const uint4*)((const __hip_bfloat16*)Av + aoff[q] + kt * 32);
      }
      rb[q] = *(const uint4*)(bg[q] + kt * 32);
    }
    __syncthreads();                      // WAR: prior ds_reads done
#pragma unroll
    for (int q = 0; q < 2; ++q) { *lAdst[q] = ra[q]; *lBdst[q] = rb[q]; }
    __syncthreads();                      // staged data visible
    bf16x8 af[4], bfr[4];
#pragma unroll
    for (int i = 0; i < 4; ++i)
      af[i] = *reinterpret_cast<const bf16x8*>(&lA[(wm * 64 + i * 16 + lrow) * 32 + quad * 8]);
#pragma unroll
    for (int j = 0; j < 4; ++j)
      bfr[j] = *reinterpret_cast<const bf16x8*>(&lB[(wn * 64 + j * 16 + lrow) * 32 + quad * 8]);
#pragma unroll
    for (int i = 0; i < 4; ++i)
#pragma unroll
      for (int j = 0; j < 4; ++j)
        acc[i][j] = __builtin_amdgcn_mfma_f32_16x16x32_bf16(af[i], bfr[j], acc[i][j], 0, 0, 0);
  }

  // epilogue: D[reg] = C[row=(lane>>4)*4+reg][col=lane&15]  (m89-verified)
#pragma unroll
  for (int i = 0; i < 4; ++i) {
    const int row0 = mt * 128 + wm * 64 + i * 16 + quad * 4;
#pragma unroll
    for (int j = 0; j < 4; ++j) {
      const int col = nt * 128 + wn * 64 + j * 16 + lrow;
      if (col >= N) continue;
#pragma unroll
      for (int rg = 0; rg < 4; ++rg) {
        const int r = row0 + rg;
        if (r >= M) continue;
        const float v = acc[i][j][rg];
        if (EPI == 0) {          // in_proj: x half -> e0, z half -> e1 (bf16)
          if (col < 384) ((__hip_bfloat16*)e0)[(size_t)r * 384 + col] = __float2bfloat16(v);
          else           ((__hip_bfloat16*)e1)[(size_t)r * 384 + (col - 384)] = __float2bfloat16(v);
        } else if (EPI == 1) {   // dt: bias+softplus (bf16); B/C (fp32)
          if (col < 384) {
            const float x = v + bf(bias[col]);
            const float sp = (x > 20.f) ? x : log1pf(__expf(x));
            ((__hip_bfloat16*)e0)[(size_t)r * 384 + col] = __float2bfloat16(sp);
          } else if (col < 416) {
            ((float*)e1)[(size_t)r * 32 + (col - 384)] = v;
          }
        } else {                 // final out: dtype per runtime flag
          if (fbf) ((__hip_bfloat16*)e0)[(size_t)r * 384 + col] = __float2bfloat16(v);
          else     ((float*)e0)[(size_t)r * 384 + col] = v;
        }
      }
    }
  }
}

// ---------------------------------------------------------------------------
// depthwise conv k=4 (taps t-1..t+2) + silu on x half; 8 channels/thread.
// (round-5 weight-indexing bug fixed in round 6: 32 bf16 weights = 4 uint4)
// ---------------------------------------------------------------------------
__global__ void convx_k(const __hip_bfloat16* __restrict__ xh,
                        const __hip_bfloat16* __restrict__ cxw,
                        __hip_bfloat16* __restrict__ xc) {
  const int idx = blockIdx.x * 256 + threadIdx.x;
  if (idx >= MTOT * 48) return;
  const int g  = idx % 48;       // channel group (8 ch)
  const int rg = idx / 48;       // token row
  const int t  = rg % L_;
  const int c0 = g * 8;
  uint4 wv[4];                   // weights: channels c0..c0+7 x 4 taps
#pragma unroll
  for (int p = 0; p < 4; ++p) wv[p] = *(const uint4*)(cxw + c0 * 4 + p * 8);
  float acc[8] = {};
#pragma unroll
  for (int k = 0; k < 4; ++k) {
    const int tt = t + k - 1;
    if (tt < 0 || tt >= L_) continue;
    const uint4 u = *(const uint4*)(xh + (size_t)(rg + k - 1) * 384 + c0);
#pragma unroll
    for (int j = 0; j < 8; ++j) {
      const int e = j * 4 + k;                      // weight flat element
      acc[j] += u16f(wv[e >> 3], e & 7) * u16f(u, j);
    }
  }
  uint4 o;
#pragma unroll
  for (int p = 0; p < 4; ++p) {
    const float s0 = acc[2 * p]     / (1.f + __expf(-acc[2 * p]));
    const float s1 = acc[2 * p + 1] / (1.f + __expf(-acc[2 * p + 1]));
    (&o.x)[p] = f2bu(s0) | ((unsigned)f2bu(s1) << 16);
  }
  *(uint4*)(xc + (size_t)rg * 384 + c0) = o;
}

// ---------------------------------------------------------------------------
// scan phase 1: per (b, chunk, d) local scan with h0=0; emits chunk decay
// P = exp2(sum(dt)*a2) and local h_end. Layout: [(c*8+b)*16+n]*384+d.
// ---------------------------------------------------------------------------
__global__ __launch_bounds__(128)
void scan1_k(const __hip_bfloat16* __restrict__ dt, const float* __restrict__ bc,
             const __hip_bfloat16* __restrict__ xc,
             const __hip_bfloat16* __restrict__ alog,
             float* __restrict__ pbuf, float* __restrict__ hend)
{
  __shared__ float lBC[CH * 32];
  const int blk = blockIdx.x;
  const int dt3 = blk % 3;
  const int c   = (blk / 3) % NCH;
  const int b   = blk / (3 * NCH);
  const int d   = dt3 * 128 + threadIdx.x;
  const int t0  = c * CH;
  const int r0  = b * L_ + t0;
  const int tmax = (L_ - t0 < CH) ? (L_ - t0) : CH;
  for (int i = threadIdx.x; i < tmax * 32; i += 128) lBC[i] = bc[(size_t)r0 * 32 + i];
  __syncthreads();

  float a2[16];
#pragma unroll
  for (int n = 0; n < 16; ++n)
    a2[n] = -1.4426950408889634f * __expf(bf(alog[d * 16 + n]));  // A * log2(e)
  float h[16];
#pragma unroll
  for (int n = 0; n < 16; ++n) h[n] = 0.f;
  float sdt = 0.f;

  for (int tt = 0; tt < tmax; ++tt) {
    const size_t r = (size_t)(r0 + tt);
    const float dtv = bf(dt[r * 384 + d]);
    const float xv  = bf(xc[r * 384 + d]);
    sdt += dtv;
    const float dtx = dtv * xv;
#pragma unroll
    for (int n = 0; n < 16; ++n)
      h[n] = h[n] * exp2f(dtv * a2[n]) + dtx * lBC[tt * 32 + n];
  }
  const size_t base = ((size_t)(c * 8 + b) * 16) * 384 + d;
#pragma unroll
  for (int n = 0; n < 16; ++n) {
    pbuf[base + n * 384] = exp2f(sdt * a2[n]);
    hend[base + n * 384] = h[n];
  }
}

// ---------------------------------------------------------------------------
// scan phase 2: cross-chunk scan per (b,d,n); rewrites pbuf with h_start
// ---------------------------------------------------------------------------
__global__ void scan2_k(float* __restrict__ pbuf, const float* __restrict__ hend) {
  const int tid = blockIdx.x * 256 + threadIdx.x;   // 49152 total
  const int d = tid % 384;
  const int n = (tid / 384) & 15;
  const int b = tid / 6144;
  float H = 0.f;
  for (int c = 0; c < NCH; ++c) {
    const size_t idx = ((size_t)(c * 8 + b) * 16 + n) * 384 + d;
    const float p = pbuf[idx];
    const float he = hend[idx];
    pbuf[idx] = H;
    H = p * H + he;
  }
}

// ---------------------------------------------------------------------------
// scan phase 3: recompute with h_start; fused z-conv + silu gate; writes
// yg = (y + D*x) * silu(conv(z)) IN PLACE over dt (same-thread RMW).
// ---------------------------------------------------------------------------
__global__ __launch_bounds__(128)
void scan3_k(__hip_bfloat16* dtyg, const float* __restrict__ bc,
             const __hip_bfloat16* __restrict__ xc,
             const __hip_bfloat16* __restrict__ zh,
             const __hip_bfloat16* __restrict__ czw,
             const __hip_bfloat16* __restrict__ alog,
             const __hip_bfloat16* __restrict__ dpar,
             const float* __restrict__ hstart)
{
  __shared__ float lBC[CH * 32];
  const int blk = blockIdx.x;
  const int dt3 = blk % 3;
  const int c   = (blk / 3) % NCH;
  const int b   = blk / (3 * NCH);
  const int d   = dt3 * 128 + threadIdx.x;
  const int t0  = c * CH;
  const int r0  = b * L_ + t0;
  const int tmax = (L_ - t0 < CH) ? (L_ - t0) : CH;
  for (int i = threadIdx.x; i < tmax * 32; i += 128) lBC[i] = bc[(size_t)r0 * 32 + i];
  __syncthreads();

  float a2[16];
#pragma unroll
  for (int n = 0; n < 16; ++n)
    a2[n] = -1.4426950408889634f * __expf(bf(alog[d * 16 + n]));
  float h[16];
  const size_t base = ((size_t)(c * 8 + b) * 16) * 384 + d;
#pragma unroll
  for (int n = 0; n < 16; ++n) h[n] = hstart[base + n * 384];
  const float Dd = bf(dpar[d]);
  float cw[4];
#pragma unroll
  for (int k = 0; k < 4; ++k) cw[k] = bf(czw[d * 4 + k]);

  float zm1 = (t0 - 1 >= 0) ? bf(zh[(size_t)(r0 - 1) * 384 + d]) : 0.f;
  float z0  = bf(zh[(size_t)r0 * 384 + d]);
  float zp1 = (t0 + 1 < L_) ? bf(zh[(size_t)(r0 + 1) * 384 + d]) : 0.f;

  for (int tt = 0; tt < tmax; ++tt) {
    const int t = t0 + tt;
    const size_t r = (size_t)(r0 + tt);
    const float zp2 = (t + 2 < L_) ? bf(zh[(r + 2) * 384 + d]) : 0.f;
    const float dtv = bf(dtyg[r * 384 + d]);
    const float xv  = bf(xc[r * 384 + d]);
    const float dtx = dtv * xv;
    float y = 0.f;
#pragma unroll
    for (int n = 0; n < 16; ++n) {
      h[n] = h[n] * exp2f(dtv * a2[n]) + dtx * lBC[tt * 32 + n];
      y += h[n] * lBC[tt * 32 + 16 + n];
    }
    y += Dd * xv;
    const float zc = cw[0] * zm1 + cw[1] * z0 + cw[2] * zp1 + cw[3] * zp2;
    const float zs = zc / (1.f + __expf(-zc));
    dtyg[r * 384 + d] = __float2bfloat16(y * zs);
    zm1 = z0; z0 = zp1; zp1 = zp2;
  }
}

// ---------------------------------------------------------------------------
extern "C" void kernel_launch(void* const* d_in, const int* in_sizes, int n_in,
                              void* d_out, int out_size, void* d_ws, size_t ws_size,
                              hipStream_t stream) {
  const void* hs   = d_in[0];
  const void* w_in = d_in[1];
  const void* cxw  = d_in[2];
  const void* czw  = d_in[3];
  const void* xw   = d_in[4];
  const void* dtw  = d_in[5];
  const void* dtb  = d_in[6];
  const void* alog = d_in[7];
  const void* dpar = d_in[8];
  const void* ow   = d_in[9];
  const int* perm  = (const int*)d_in[10];
  const int* permr = (const int*)d_in[11];

  char* ws = (char*)d_ws;
  size_t off = 0;
  auto alloc = [&](size_t nbytes) -> char* {
    char* p = ws + off;
    off += (nbytes + 255) & ~(size_t)255;
    return p;
  };
  int* flag              = (int*)alloc(256);
  int* nperm             = (int*)alloc(4096 * 4);
  int* npermr            = (int*)alloc(4096 * 4);
  __hip_bfloat16* w_inb  = (__hip_bfloat16*)alloc(294912 * 2);
  __hip_bfloat16* cxwb   = (__hip_bfloat16*)alloc(1536 * 2);
  __hip_bfloat16* czwb   = (__hip_bfloat16*)alloc(1536 * 2);
  __hip_bfloat16* xwb    = (__hip_bfloat16*)alloc(21504 * 2);
  __hip_bfloat16* dtwb   = (__hip_bfloat16*)alloc(9216 * 2);
  __hip_bfloat16* dtbb   = (__hip_bfloat16*)alloc(384 * 2);
  __hip_bfloat16* alogb  = (__hip_bfloat16*)alloc(6144 * 2);
  __hip_bfloat16* dparb  = (__hip_bfloat16*)alloc(384 * 2);
  __hip_bfloat16* owb    = (__hip_bfloat16*)alloc(147456 * 2);
  __hip_bfloat16* wcombb = (__hip_bfloat16*)alloc((size_t)512 * 384 * 2);
  __hip_bfloat16* zh     = (__hip_bfloat16*)alloc((size_t)MTOT * 384 * 2);  // 25.2 MB
  __hip_bfloat16* xc     = (__hip_bfloat16*)alloc((size_t)MTOT * 384 * 2);  // 25.2 MB
  __hip_bfloat16* dtyg   = (__hip_bfloat16*)alloc((size_t)MTOT * 384 * 2);  // 25.2 MB
  float*          bcf    = (float*)alloc((size_t)MTOT * 32 * 4);            // 4.2 MB
  // d_out as scratch: xh (bf16, dies at convx), then pbuf+hend (16.9 MB)
  __hip_bfloat16* xh   = (__hip_bfloat16*)d_out;
  float*          pbuf = (float*)d_out;
  float*          hend = (float*)((char*)d_out + (size_t)NCH * B_ * NS * DH * 4);

  // 0) dtype + perm normalization
  flag_k<<<1, 64, 0, stream>>>(hs, flag);
  perm_k<<<2, 1024, 0, stream>>>(perm, permr, nperm, npermr);
  NormSet ns;
  ns.src[0] = w_in; ns.dst[0] = w_inb; ns.n[0] = 294912;
  ns.src[1] = ow;   ns.dst[1] = owb;   ns.n[1] = 147456;
  ns.src[2] = xw;   ns.dst[2] = xwb;   ns.n[2] = 21504;
  ns.src[3] = dtw;  ns.dst[3] = dtwb;  ns.n[3] = 9216;
  ns.src[4] = alog; ns.dst[4] = alogb; ns.n[4] = 6144;
  ns.src[5] = cxw;  ns.dst[5] = cxwb;  ns.n[5] = 1536;
  ns.src[6] = czw;  ns.dst[6] = czwb;  ns.n[6] = 1536;
  ns.src[7] = dtb;  ns.dst[7] = dtbb;  ns.n[7] = 384;
  ns.src[8] = dpar; ns.dst[8] = dparb; ns.n[8] = 384;
  norm_all<<<1152, 256, 0, stream>>>(ns, flag);
  // 1) fused dt/BC weight build
  prep_k<<<768, 256, 0, stream>>>(dtwb, xwb, wcombb);
  // 2) in_proj MFMA GEMM + perm gather -> xh (d_out), zh
  gemm_k<1, 1, 0><<<dim3(6, 257), 256, 0, stream>>>(
      hs, w_inb, xh, zh, nullptr, nperm, flag, MTOT, 768);
  // 3) depthwise conv + silu on x half (8 ch/thread)
  convx_k<<<(MTOT * 48 + 255) / 256, 256, 0, stream>>>(xh, cxwb, xc);
  // 4) fused dt (bias+softplus, bf16) and B/C (fp32) MFMA GEMM
  gemm_k<0, 0, 1><<<dim3(4, 257), 256, 0, stream>>>(
      xc, wcombb, dtyg, bcf, dtbb, nullptr, flag, MTOT, 512);
  // 5) chunked selective scan (z-conv + gate fused into phase 3)
  scan1_k<<<B_ * NCH * 3, 128, 0, stream>>>(dtyg, bcf, xc, alogb, pbuf, hend);
  scan2_k<<<192, 256, 0, stream>>>(pbuf, hend);
  scan3_k<<<B_ * NCH * 3, 128, 0, stream>>>(dtyg, bcf, xc, zh, czwb, alogb,
                                            dparb, pbuf);
  // 6) out_proj MFMA GEMM with inverse-perm gather -> final output
  gemm_k<0, 1, 2><<<dim3(3, 257), 256, 0, stream>>>(
      dtyg, owb, d_out, nullptr, nullptr, npermr, flag, MTOT, 384);
  (void)in_sizes; (void)n_in; (void)out_size; (void)ws_size;
}

// Round 8
// 590.074 us; speedup vs baseline: 1.6734x; 1.1172x over previous
//
#include <hip/hip_runtime.h>
#include <hip/hip_bf16.h>

#define DEVI __device__ __forceinline__

constexpr int B_   = 8;
constexpr int L_   = 4097;
constexpr int MTOT = B_ * L_;          // 32776 tokens
constexpr int DH   = 384;              // d_half
constexpr int NS   = 16;               // d_state
constexpr int CH   = 48;               // scan chunk length (48 -> 2064 blocks, ~16 waves/CU)
constexpr int NCH  = (L_ + CH - 1) / CH;  // 86 chunks (last has 17 tokens)

typedef __bf16 bf16x8 __attribute__((ext_vector_type(8)));
typedef float  f32x4  __attribute__((ext_vector_type(4)));

DEVI float bl(unsigned v) { return __uint_as_float(v << 16); }          // low bf16
DEVI float bh(unsigned v) { return __uint_as_float(v & 0xffff0000u); }  // high bf16
DEVI float bf(const __hip_bfloat16 x) { return __bfloat162float(x); }
DEVI unsigned short f2bu(float x) {
  __hip_bfloat16 b = __float2bfloat16(x);
  return *(unsigned short*)&b;
}
DEVI float u16f(const uint4& u, int j) {   // element j (0..7) of 8 packed bf16
  const unsigned w = (&u.x)[j >> 1];
  return (j & 1) ? bh(w) : bl(w);
}

// ---------------------------------------------------------------------------
// dtype detector: hidden_states ~ N(0,1). bf16 -> every even u16 has exponent
// field ~126; fp32 -> even u16 are mantissa bits (uniform). flag=1 -> bf16.
// (round-7 evidence: harness preserves reference dtypes -> fp32 + int64 perm)
// ---------------------------------------------------------------------------
__global__ void flag_k(const void* hs, int* flagp) {
  if (threadIdx.x == 0 && blockIdx.x == 0) {
    const unsigned short* u = (const unsigned short*)hs;
    int ok = 1;
    for (int i = 0; i < 8; ++i) {
      const unsigned short v = u[2 * i];
      const int e = (v >> 7) & 0xFF;
      if (!(v == 0 || (e >= 100 && e <= 140))) ok = 0;
    }
    flagp[0] = ok;
  }
}

// ---------------------------------------------------------------------------
// perm normalizer: int64 storage has all odd int32 words zero (values<4096).
// ---------------------------------------------------------------------------
__global__ void perm_k(const int* p0, const int* p1, int* d0, int* d1) {
  __shared__ int s_or;
  const int* src = blockIdx.x ? p1 : p0;
  int*       dst = blockIdx.x ? d1 : d0;
  if (threadIdx.x == 0) s_or = 0;
  __syncthreads();
  int loc = 0;
  for (int i = threadIdx.x; i < 2048; i += 1024) loc |= src[2 * i + 1];
  atomicOr(&s_or, loc);
  __syncthreads();
  const bool is64 = (s_or == 0);
  for (int j = threadIdx.x; j < 4096; j += 1024)
    dst[j] = is64 ? (int)((const long long*)src)[j] : src[j];
}

// ---------------------------------------------------------------------------
// fused normalization of all 9 weight tensors to bf16 (one launch)
// ---------------------------------------------------------------------------
struct NormSet { const void* src[9]; void* dst[9]; int n[9]; };
__global__ void norm_all(NormSet s, const int* flagp) {
  const int idx = blockIdx.x * 256 + threadIdx.x;
  const int f = flagp[0];
#pragma unroll
  for (int t = 0; t < 9; ++t) {
    if (idx < s.n[t]) {
      __hip_bfloat16* d = (__hip_bfloat16*)s.dst[t];
      if (f) d[idx] = ((const __hip_bfloat16*)s.src[t])[idx];
      else   d[idx] = __float2bfloat16(((const float*)s.src[t])[idx]);
    }
  }
}

// ---------------------------------------------------------------------------
// Wcomb bf16 (512 x 384): rows 0..383 = dt_proj_w @ x_proj_w[0:24] (fused dt
// matrix), rows 384..415 = x_proj_w[24:56] (B then C), rows 416..511 = 0.
// ---------------------------------------------------------------------------
__global__ void prep_k(const __hip_bfloat16* __restrict__ dtw,
                       const __hip_bfloat16* __restrict__ xw,
                       __hip_bfloat16* __restrict__ wcomb) {
  const int idx = blockIdx.x * 256 + threadIdx.x;
  if (idx >= 512 * 384) return;
  const int n = idx / 384, k = idx - n * 384;
  float v = 0.f;
  if (n < 384) {
#pragma unroll
    for (int r = 0; r < 24; ++r) v += bf(dtw[n * 24 + r]) * bf(xw[r * 384 + k]);
  } else if (n < 416) {
    v = bf(xw[(24 + n - 384) * 384 + k]);
  }
  wcomb[idx] = __float2bfloat16(v);
}

// ---------------------------------------------------------------------------
// MFMA GEMM: C[m,n] = sum_k A[src(m),k] * W[n,k], K=384, 128x128 tile,
// 4 waves x (4x4) 16x16x32 bf16 subtiles. Register staging, SOFTWARE-
// PIPELINED: tile kt+1 is fetched into VGPRs right after barrier-2 so its
// ~900-cyc latency overlaps the MFMA phase (round 7: loads were issued
// immediately before the vmcnt-draining barrier -> zero overlap).
// Grid: (Ntiles, 257) with nt = blockIdx.x fastest for L2 A-reuse.
// ---------------------------------------------------------------------------
template<int AD, int GATHER, int EPI>
__global__ __launch_bounds__(256, 2)
void gemm_k(const void* __restrict__ Av, const __hip_bfloat16* __restrict__ W,
            void* __restrict__ e0, void* __restrict__ e1,
            const __hip_bfloat16* __restrict__ bias,
            const int* __restrict__ gidx, const int* __restrict__ flagp,
            int M, int N)
{
  __shared__ __align__(16) __hip_bfloat16 lA[128 * 32];
  __shared__ __align__(16) __hip_bfloat16 lB[128 * 32];
  const int tid  = threadIdx.x;
  const int lane = tid & 63;
  const int wv   = tid >> 6;
  const int wm   = wv >> 1, wn = wv & 1;
  const int nt   = blockIdx.x, mt = blockIdx.y;
  const int kcol = (lane & 3) * 8;        // element offset within BK=32 row
  const int fbf  = flagp[0];              // 1 = bf16 external storage

  size_t aoff[2];
  const __hip_bfloat16* bg[2];
#pragma unroll
  for (int q = 0; q < 2; ++q) {
    const int seg = wv * 2 + q;
    int r = mt * 128 + seg * 16 + (lane >> 2);
    if (r >= M) r = M - 1;                // tail tile: duplicate a valid row
    int src;
    if (GATHER) { const int b = r / L_, t = r - b * L_;
                  src = b * L_ + (t == 0 ? 0 : 1 + gidx[t - 1]); }
    else        { src = r; }
    aoff[q] = (size_t)src * 384 + kcol;
    const int nr = nt * 128 + seg * 16 + (lane >> 2);
    bg[q] = W + (size_t)nr * 384 + kcol;
  }
  uint4* lAdst[2];
  uint4* lBdst[2];
#pragma unroll
  for (int q = 0; q < 2; ++q) {
    const int seg = wv * 2 + q;
    lAdst[q] = reinterpret_cast<uint4*>(&lA[seg * 512 + lane * 8]);
    lBdst[q] = reinterpret_cast<uint4*>(&lB[seg * 512 + lane * 8]);
  }

  uint4 pa[2][2], pb[2];                  // prefetch registers
  auto fetch = [&](int kt) {
#pragma unroll
    for (int q = 0; q < 2; ++q) {
      if (AD == 1 && !fbf) {              // fp32 A storage: raw fetch, convert later
        const float* f = (const float*)Av + aoff[q] + (size_t)kt * 32;
        pa[q][0] = *(const uint4*)f;
        pa[q][1] = *(const uint4*)(f + 4);
      } else {
        pa[q][0] = *(const uint4*)((const __hip_bfloat16*)Av + aoff[q] + kt * 32);
      }
      pb[q] = *(const uint4*)(bg[q] + kt * 32);
    }
  };
  auto stage = [&]() {
#pragma unroll
    for (int q = 0; q < 2; ++q) {
      uint4 r;
      if (AD == 1 && !fbf) {              // convert fp32 -> packed bf16 at store
        const float4 f0 = *(const float4*)&pa[q][0];
        const float4 f1 = *(const float4*)&pa[q][1];
        r.x = f2bu(f0.x) | ((unsigned)f2bu(f0.y) << 16);
        r.y = f2bu(f0.z) | ((unsigned)f2bu(f0.w) << 16);
        r.z = f2bu(f1.x) | ((unsigned)f2bu(f1.y) << 16);
        r.w = f2bu(f1.z) | ((unsigned)f2bu(f1.w) << 16);
      } else {
        r = pa[q][0];
      }
      *lAdst[q] = r;
      *lBdst[q] = pb[q];
    }
  };

  f32x4 acc[4][4] = {};
  const int lrow = lane & 15, quad = lane >> 4;

  fetch(0);
  for (int kt = 0; kt < 12; ++kt) {       // K = 12 * 32
    __syncthreads();                      // WAR: prior ds_reads done (drains vmcnt)
    stage();
    __syncthreads();                      // staged data visible
    if (kt < 11) fetch(kt + 1);           // in flight across the MFMA phase
    bf16x8 af[4], bfr[4];
#pragma unroll
    for (int i = 0; i < 4; ++i)
      af[i] = *reinterpret_cast<const bf16x8*>(&lA[(wm * 64 + i * 16 + lrow) * 32 + quad * 8]);
#pragma unroll
    for (int j = 0; j < 4; ++j)
      bfr[j] = *reinterpret_cast<const bf16x8*>(&lB[(wn * 64 + j * 16 + lrow) * 32 + quad * 8]);
#pragma unroll
    for (int i = 0; i < 4; ++i)
#pragma unroll
      for (int j = 0; j < 4; ++j)
        acc[i][j] = __builtin_amdgcn_mfma_f32_16x16x32_bf16(af[i], bfr[j], acc[i][j], 0, 0, 0);
  }

  // epilogue: D[reg] = C[row=(lane>>4)*4+reg][col=lane&15]  (m89-verified)
#pragma unroll
  for (int i = 0; i < 4; ++i) {
    const int row0 = mt * 128 + wm * 64 + i * 16 + quad * 4;
#pragma unroll
    for (int j = 0; j < 4; ++j) {
      const int col = nt * 128 + wn * 64 + j * 16 + lrow;
      if (col >= N) continue;
#pragma unroll
      for (int rg = 0; rg < 4; ++rg) {
        const int r = row0 + rg;
        if (r >= M) continue;
        const float v = acc[i][j][rg];
        if (EPI == 0) {          // in_proj: x half -> e0, z half -> e1 (bf16)
          if (col < 384) ((__hip_bfloat16*)e0)[(size_t)r * 384 + col] = __float2bfloat16(v);
          else           ((__hip_bfloat16*)e1)[(size_t)r * 384 + (col - 384)] = __float2bfloat16(v);
        } else if (EPI == 1) {   // dt: bias+softplus (bf16); B/C (fp32)
          if (col < 384) {
            const float x = v + bf(bias[col]);
            const float sp = (x > 20.f) ? x : log1pf(__expf(x));
            ((__hip_bfloat16*)e0)[(size_t)r * 384 + col] = __float2bfloat16(sp);
          } else if (col < 416) {
            ((float*)e1)[(size_t)r * 32 + (col - 384)] = v;
          }
        } else {                 // final out: dtype per runtime flag
          if (fbf) ((__hip_bfloat16*)e0)[(size_t)r * 384 + col] = __float2bfloat16(v);
          else     ((float*)e0)[(size_t)r * 384 + col] = v;
        }
      }
    }
  }
}

// ---------------------------------------------------------------------------
// depthwise conv k=4 (taps t-1..t+2) + silu on x half; 8 channels/thread.
// ---------------------------------------------------------------------------
__global__ void convx_k(const __hip_bfloat16* __restrict__ xh,
                        const __hip_bfloat16* __restrict__ cxw,
                        __hip_bfloat16* __restrict__ xc) {
  const int idx = blockIdx.x * 256 + threadIdx.x;
  if (idx >= MTOT * 48) return;
  const int g  = idx % 48;       // channel group (8 ch)
  const int rg = idx / 48;       // token row
  const int t  = rg % L_;
  const int c0 = g * 8;
  uint4 wv[4];                   // weights: channels c0..c0+7 x 4 taps
#pragma unroll
  for (int p = 0; p < 4; ++p) wv[p] = *(const uint4*)(cxw + c0 * 4 + p * 8);
  float acc[8] = {};
#pragma unroll
  for (int k = 0; k < 4; ++k) {
    const int tt = t + k - 1;
    if (tt < 0 || tt >= L_) continue;
    const uint4 u = *(const uint4*)(xh + (size_t)(rg + k - 1) * 384 + c0);
#pragma unroll
    for (int j = 0; j < 8; ++j) {
      const int e = j * 4 + k;                      // weight flat element
      acc[j] += u16f(wv[e >> 3], e & 7) * u16f(u, j);
    }
  }
  uint4 o;
#pragma unroll
  for (int p = 0; p < 4; ++p) {
    const float s0 = acc[2 * p]     / (1.f + __expf(-acc[2 * p]));
    const float s1 = acc[2 * p + 1] / (1.f + __expf(-acc[2 * p + 1]));
    (&o.x)[p] = f2bu(s0) | ((unsigned)f2bu(s1) << 16);
  }
  *(uint4*)(xc + (size_t)rg * 384 + c0) = o;
}

// ---------------------------------------------------------------------------
// scan phase 1: per (b, chunk, d) local scan with h0=0. Emits:
//   - y_local = C . h_local + D*x  (bf16, IN PLACE over xc -- same thread RMW)
//   - chunk decay P = exp2(sum(dt)*a2) and h_end into pbuf/hend.
// Identity used: h(t) = h_local(t) + cumP(t) (.) h_start, so phase 3 only
// needs a correction term (round-7 scan3 recomputed the full h chain).
// ---------------------------------------------------------------------------
__global__ __launch_bounds__(128)
void scan1_k(const __hip_bfloat16* __restrict__ dt, const float* __restrict__ bc,
             __hip_bfloat16* xcio,
             const __hip_bfloat16* __restrict__ alog,
             const __hip_bfloat16* __restrict__ dpar,
             float* __restrict__ pbuf, float* __restrict__ hend)
{
  __shared__ float lBC[CH * 32];
  const int blk = blockIdx.x;
  const int dt3 = blk % 3;
  const int c   = (blk / 3) % NCH;
  const int b   = blk / (3 * NCH);
  const int d   = dt3 * 128 + threadIdx.x;
  const int t0  = c * CH;
  const int r0  = b * L_ + t0;
  const int tmax = (L_ - t0 < CH) ? (L_ - t0) : CH;
  for (int i = threadIdx.x; i < tmax * 32; i += 128) lBC[i] = bc[(size_t)r0 * 32 + i];
  __syncthreads();

  float a2[16];
#pragma unroll
  for (int n = 0; n < 16; ++n)
    a2[n] = -1.4426950408889634f * __expf(bf(alog[d * 16 + n]));  // A * log2(e)
  float h[16];
#pragma unroll
  for (int n = 0; n < 16; ++n) h[n] = 0.f;
  float sdt = 0.f;
  const float Dd = bf(dpar[d]);

  for (int tt = 0; tt < tmax; ++tt) {
    const size_t r = (size_t)(r0 + tt);
    const float dtv = bf(dt[r * 384 + d]);
    const float xv  = bf(xcio[r * 384 + d]);
    sdt += dtv;
    const float dtx = dtv * xv;
    float y = 0.f;
#pragma unroll
    for (int n = 0; n < 16; ++n) {
      h[n] = h[n] * exp2f(dtv * a2[n]) + dtx * lBC[tt * 32 + n];
      y += h[n] * lBC[tt * 32 + 16 + n];
    }
    y += Dd * xv;
    xcio[r * 384 + d] = __float2bfloat16(y);   // y_local, in place over x
  }
  const size_t base = ((size_t)(c * 8 + b) * 16) * 384 + d;
#pragma unroll
  for (int n = 0; n < 16; ++n) {
    pbuf[base + n * 384] = exp2f(sdt * a2[n]);
    hend[base + n * 384] = h[n];
  }
}

// ---------------------------------------------------------------------------
// scan phase 2: cross-chunk scan per (b,d,n); rewrites pbuf with h_start
// ---------------------------------------------------------------------------
__global__ void scan2_k(float* __restrict__ pbuf, const float* __restrict__ hend) {
  const int tid = blockIdx.x * 256 + threadIdx.x;   // 49152 total
  const int d = tid % 384;
  const int n = (tid / 384) & 15;
  const int b = tid / 6144;
  float H = 0.f;
  for (int c = 0; c < NCH; ++c) {
    const size_t idx = ((size_t)(c * 8 + b) * 16 + n) * 384 + d;
    const float p = pbuf[idx];
    const float he = hend[idx];
    pbuf[idx] = H;
    H = p * H + he;
  }
}

// ---------------------------------------------------------------------------
// scan phase 3 (light): y(t) = y_local(t) + sum_n C(t,n)*exp2(sdt(t)*a2[n])*
// h_start[n]; then fused z-conv + silu gate. Writes IN PLACE over dt (dtyg).
// Only C is staged in LDS (B no longer needed here).
// ---------------------------------------------------------------------------
__global__ __launch_bounds__(128)
void scan3_k(__hip_bfloat16* dtyg, const float* __restrict__ bc,
             const __hip_bfloat16* __restrict__ yl,
             const __hip_bfloat16* __restrict__ zh,
             const __hip_bfloat16* __restrict__ czw,
             const __hip_bfloat16* __restrict__ alog,
             const float* __restrict__ hstart)
{
  __shared__ float lC[CH * 16];
  const int blk = blockIdx.x;
  const int dt3 = blk % 3;
  const int c   = (blk / 3) % NCH;
  const int b   = blk / (3 * NCH);
  const int d   = dt3 * 128 + threadIdx.x;
  const int t0  = c * CH;
  const int r0  = b * L_ + t0;
  const int tmax = (L_ - t0 < CH) ? (L_ - t0) : CH;
  for (int i = threadIdx.x; i < tmax * 16; i += 128)
    lC[i] = bc[(size_t)r0 * 32 + (i >> 4) * 32 + 16 + (i & 15)];
  __syncthreads();

  float a2[16];
#pragma unroll
  for (int n = 0; n < 16; ++n)
    a2[n] = -1.4426950408889634f * __expf(bf(alog[d * 16 + n]));
  float hs_[16];
  const size_t base = ((size_t)(c * 8 + b) * 16) * 384 + d;
#pragma unroll
  for (int n = 0; n < 16; ++n) hs_[n] = hstart[base + n * 384];
  float cw[4];
#pragma unroll
  for (int k = 0; k < 4; ++k) cw[k] = bf(czw[d * 4 + k]);

  float zm1 = (t0 - 1 >= 0) ? bf(zh[(size_t)(r0 - 1) * 384 + d]) : 0.f;
  float z0  = bf(zh[(size_t)r0 * 384 + d]);
  float zp1 = (t0 + 1 < L_) ? bf(zh[(size_t)(r0 + 1) * 384 + d]) : 0.f;
  float sdt = 0.f;

  for (int tt = 0; tt < tmax; ++tt) {
    const int t = t0 + tt;
    const size_t r = (size_t)(r0 + tt);
    const float zp2 = (t + 2 < L_) ? bf(zh[(r + 2) * 384 + d]) : 0.f;
    const float dtv = bf(dtyg[r * 384 + d]);
    sdt += dtv;
    float corr = 0.f;
#pragma unroll
    for (int n = 0; n < 16; ++n)
      corr += lC[tt * 16 + n] * hs_[n] * exp2f(sdt * a2[n]);
    const float y = bf(yl[r * 384 + d]) + corr;
    const float zc = cw[0] * zm1 + cw[1] * z0 + cw[2] * zp1 + cw[3] * zp2;
    const float zs = zc / (1.f + __expf(-zc));
    dtyg[r * 384 + d] = __float2bfloat16(y * zs);
    zm1 = z0; z0 = zp1; zp1 = zp2;
  }
}

// ---------------------------------------------------------------------------
extern "C" void kernel_launch(void* const* d_in, const int* in_sizes, int n_in,
                              void* d_out, int out_size, void* d_ws, size_t ws_size,
                              hipStream_t stream) {
  const void* hs   = d_in[0];
  const void* w_in = d_in[1];
  const void* cxw  = d_in[2];
  const void* czw  = d_in[3];
  const void* xw   = d_in[4];
  const void* dtw  = d_in[5];
  const void* dtb  = d_in[6];
  const void* alog = d_in[7];
  const void* dpar = d_in[8];
  const void* ow   = d_in[9];
  const int* perm  = (const int*)d_in[10];
  const int* permr = (const int*)d_in[11];

  char* ws = (char*)d_ws;
  size_t off = 0;
  auto alloc = [&](size_t nbytes) -> char* {
    char* p = ws + off;
    off += (nbytes + 255) & ~(size_t)255;
    return p;
  };
  int* flag              = (int*)alloc(256);
  int* nperm             = (int*)alloc(4096 * 4);
  int* npermr            = (int*)alloc(4096 * 4);
  __hip_bfloat16* w_inb  = (__hip_bfloat16*)alloc(294912 * 2);
  __hip_bfloat16* cxwb   = (__hip_bfloat16*)alloc(1536 * 2);
  __hip_bfloat16* czwb   = (__hip_bfloat16*)alloc(1536 * 2);
  __hip_bfloat16* xwb    = (__hip_bfloat16*)alloc(21504 * 2);
  __hip_bfloat16* dtwb   = (__hip_bfloat16*)alloc(9216 * 2);
  __hip_bfloat16* dtbb   = (__hip_bfloat16*)alloc(384 * 2);
  __hip_bfloat16* alogb  = (__hip_bfloat16*)alloc(6144 * 2);
  __hip_bfloat16* dparb  = (__hip_bfloat16*)alloc(384 * 2);
  __hip_bfloat16* owb    = (__hip_bfloat16*)alloc(147456 * 2);
  __hip_bfloat16* wcombb = (__hip_bfloat16*)alloc((size_t)512 * 384 * 2);
  __hip_bfloat16* zh     = (__hip_bfloat16*)alloc((size_t)MTOT * 384 * 2);  // 25.2 MB
  __hip_bfloat16* xc     = (__hip_bfloat16*)alloc((size_t)MTOT * 384 * 2);  // 25.2 MB
  __hip_bfloat16* dtyg   = (__hip_bfloat16*)alloc((size_t)MTOT * 384 * 2);  // 25.2 MB
  float*          bcf    = (float*)alloc((size_t)MTOT * 32 * 4);            // 4.2 MB
  // d_out as scratch: xh (bf16, dies at convx), then pbuf+hend (33.8 MB of 50.3)
  __hip_bfloat16* xh   = (__hip_bfloat16*)d_out;
  float*          pbuf = (float*)d_out;
  float*          hend = (float*)((char*)d_out + (size_t)NCH * B_ * NS * DH * 4);

  // 0) dtype + perm normalization
  flag_k<<<1, 64, 0, stream>>>(hs, flag);
  perm_k<<<2, 1024, 0, stream>>>(perm, permr, nperm, npermr);
  NormSet ns;
  ns.src[0] = w_in; ns.dst[0] = w_inb; ns.n[0] = 294912;
  ns.src[1] = ow;   ns.dst[1] = owb;   ns.n[1] = 147456;
  ns.src[2] = xw;   ns.dst[2] = xwb;   ns.n[2] = 21504;
  ns.src[3] = dtw;  ns.dst[3] = dtwb;  ns.n[3] = 9216;
  ns.src[4] = alog; ns.dst[4] = alogb; ns.n[4] = 6144;
  ns.src[5] = cxw;  ns.dst[5] = cxwb;  ns.n[5] = 1536;
  ns.src[6] = czw;  ns.dst[6] = czwb;  ns.n[6] = 1536;
  ns.src[7] = dtb;  ns.dst[7] = dtbb;  ns.n[7] = 384;
  ns.src[8] = dpar; ns.dst[8] = dparb; ns.n[8] = 384;
  norm_all<<<1152, 256, 0, stream>>>(ns, flag);
  // 1) fused dt/BC weight build
  prep_k<<<768, 256, 0, stream>>>(dtwb, xwb, wcombb);
  // 2) in_proj MFMA GEMM + perm gather -> xh (d_out), zh
  gemm_k<1, 1, 0><<<dim3(6, 257), 256, 0, stream>>>(
      hs, w_inb, xh, zh, nullptr, nperm, flag, MTOT, 768);
  // 3) depthwise conv + silu on x half (8 ch/thread)
  convx_k<<<(MTOT * 48 + 255) / 256, 256, 0, stream>>>(xh, cxwb, xc);
  // 4) fused dt (bias+softplus, bf16) and B/C (fp32) MFMA GEMM
  gemm_k<0, 0, 1><<<dim3(4, 257), 256, 0, stream>>>(
      xc, wcombb, dtyg, bcf, dtbb, nullptr, flag, MTOT, 512);
  // 5) chunked selective scan (y_local in phase 1; light correction phase 3)
  scan1_k<<<B_ * NCH * 3, 128, 0, stream>>>(dtyg, bcf, xc, alogb, dparb, pbuf, hend);
  scan2_k<<<192, 256, 0, stream>>>(pbuf, hend);
  scan3_k<<<B_ * NCH * 3, 128, 0, stream>>>(dtyg, bcf, xc, zh, czwb, alogb, pbuf);
  // 6) out_proj MFMA GEMM with inverse-perm gather -> final output
  gemm_k<0, 1, 2><<<dim3(3, 257), 256, 0, stream>>>(
      dtyg, owb, d_out, nullptr, nullptr, npermr, flag, MTOT, 384);
  (void)in_sizes; (void)n_in; (void)out_size; (void)ws_size;
}